// Round 8
// baseline (337.720 us; speedup 1.0000x reference)
//
#include <hip/hip_runtime.h>
#include <hip/hip_cooperative_groups.h>
#include <math.h>

namespace cg = cooperative_groups;

#define GRIDN 1024
#define NAGENTS 262144
#define CCH 8
#define HIDDEN 64
#define DT 0.1f
#define DECAYF 0.99f
#define SENSOR_LEN 3.0f
// cos(0.6), sin(0.6)
#define COS_SA 0.82533561490967829724f
#define SIN_SA 0.56464247339503535720f

#define NBLK 1024   // cooperative grid: 4 blocks/CU x 256 CUs (guaranteed fit)
#define NVB  4096   // virtual blocks per phase

typedef __attribute__((ext_vector_type(8))) short short8;
typedef __attribute__((ext_vector_type(2))) _Float16 half2v;

// packed 2-way f16 dot with f32 accumulate: v_dot2_f32_f16
__device__ __forceinline__ float dot2f(unsigned a, unsigned b, float c) {
#if __has_builtin(__builtin_amdgcn_fdot2)
    return __builtin_amdgcn_fdot2(__builtin_bit_cast(half2v, a),
                                  __builtin_bit_cast(half2v, b), c, false);
#else
    half2v ha = __builtin_bit_cast(half2v, a), hb = __builtin_bit_cast(half2v, b);
    return c + (float)ha.x * (float)hb.x + (float)ha.y * (float)hb.y;
#endif
}

__device__ __forceinline__ unsigned packh(float a, float b) {
    _Float16 ha = (_Float16)a, hb = (_Float16)b;
    unsigned short ua = __builtin_bit_cast(unsigned short, ha);
    unsigned short ub = __builtin_bit_cast(unsigned short, hb);
    return (unsigned)ua | ((unsigned)ub << 16);
}

// tanh(x) = (2^(2x*log2e) - 1) / (2^(2x*log2e) + 1), clamped so exp2 can't overflow
__device__ __forceinline__ float fast_tanh(float x) {
    float xc = fminf(fmaxf(x, -9.0f), 9.0f);
    float t = __builtin_amdgcn_exp2f(xc * 2.88539008177792681472f);  // 2*log2(e)
    return (t - 1.0f) * __builtin_amdgcn_rcpf(t + 1.0f);
}

// ---------------- shared phase bodies (used by fused AND fallback) ----------------

__device__ __forceinline__ void do_pack(int tid,
                                        const float* __restrict__ W1,
                                        const float* __restrict__ W2,
                                        unsigned* __restrict__ W1p,
                                        unsigned* __restrict__ W2p) {
    for (int t = tid; t < 768 + 512; t += 256) {
        if (t < 768) {
            int p = t >> 6, j = t & 63;
            W1p[t] = packh(W1[(2 * p) * HIDDEN + j], W1[(2 * p + 1) * HIDDEN + j]);
        } else {
            int q = t - 768;
            int pg = q >> 4, k = q & 15;
            unsigned v = 0;
            if (k < 10) v = packh(W2[(2 * pg) * 10 + k], W2[(2 * pg + 1) * 10 + k]);
            W2p[q] = v;
        }
    }
}

__device__ __forceinline__ void do_box(int vb, int tid,
                                       const float* __restrict__ lat,
                                       _Float16* __restrict__ BT,
                                       int* __restrict__ winner) {
    int idx = vb * 256 + tid;  // 0 .. 1M-1
    winner[idx] = -1;
    int x = idx >> 10, y = idx & (GRIDN - 1);
    int xm = (x + GRIDN - 1) & (GRIDN - 1), xp = (x + 1) & (GRIDN - 1);
    int ym = (y + GRIDN - 1) & (GRIDN - 1), yp = (y + 1) & (GRIDN - 1);
    _Float16 out[CCH];
#pragma unroll
    for (int c = 0; c < CCH; ++c) {
        const float* L = lat + (size_t)c * GRIDN * GRIDN;
        const float* r0 = L + xm * GRIDN;
        const float* r1 = L + x * GRIDN;
        const float* r2 = L + xp * GRIDN;
        float s = r0[ym] + r0[y] + r0[yp]
                + r1[ym] + r1[y] + r1[yp]
                + r2[ym] + r2[y] + r2[yp];
        out[c] = (_Float16)s;
    }
    *(short8*)(BT + (size_t)idx * CCH) = *(const short8*)out;
}

__device__ __forceinline__ void do_agent(int vb, int lane, int wq,
                                         float (*part)[64][13],
                                         const float* __restrict__ pos,
                                         const float* __restrict__ vel,
                                         const _Float16* __restrict__ BT,
                                         const unsigned* __restrict__ W1p,
                                         const float* __restrict__ b1,
                                         const unsigned* __restrict__ W2p,
                                         const float* __restrict__ b2,
                                         float* __restrict__ out_pos,
                                         float* __restrict__ out_vel,
                                         float* __restrict__ dp,
                                         int* __restrict__ winner) {
    int i = vb * 64 + lane;  // agent

    float px = pos[i], py = pos[i + NAGENTS];
    float vx = vel[i], vy = vel[i + NAGENTS];

    float r2 = vx * vx + vy * vy;
    float ct, st;
    if (r2 > 0.f) {
        float inv = rsqrtf(r2);
        ct = vx * inv;
        st = vy * inv;
    } else {
        ct = 1.f;  // atan2(0,0) = 0
        st = 0.f;
    }

    // sensor directions: front, +0.6 (left), -0.6 (right)
    float dirx[3], diry[3];
    dirx[0] = ct;                          diry[0] = st;
    dirx[1] = ct * COS_SA - st * SIN_SA;   diry[1] = st * COS_SA + ct * SIN_SA;
    dirx[2] = ct * COS_SA + st * SIN_SA;   diry[2] = st * COS_SA - ct * SIN_SA;

    uint4 raw[3];
#pragma unroll
    for (int s = 0; s < 3; ++s) {
        int gx = ((int)rintf(px + SENSOR_LEN * dirx[s]) + GRIDN) & (GRIDN - 1);
        int gy = ((int)rintf(py + SENSOR_LEN * diry[s]) + GRIDN) & (GRIDN - 1);
        raw[s] = *(const uint4*)(BT + ((size_t)(gx << 10) + gy) * CCH);
    }
    // xk[p] = f16 pair (x[2p], x[2p+1]); x = [front8, left8, right8]
    unsigned xk[12];
#pragma unroll
    for (int s = 0; s < 3; ++s) {
        xk[s * 4 + 0] = raw[s].x; xk[s * 4 + 1] = raw[s].y;
        xk[s * 4 + 2] = raw[s].z; xk[s * 4 + 3] = raw[s].w;
    }

    // layer 1: h[jj] = b1[wq*16+jj] + sum_p dot2(xk[p], W1pair[p][wq*16+jj])
    float h[16];
    {
        const float4* b1v = (const float4*)(b1 + wq * 16);
#pragma unroll
        for (int q = 0; q < 4; ++q) {
            float4 b = b1v[q];
            h[q * 4 + 0] = b.x; h[q * 4 + 1] = b.y;
            h[q * 4 + 2] = b.z; h[q * 4 + 3] = b.w;
        }
    }
#pragma unroll
    for (int p = 0; p < 12; ++p) {
        unsigned xp = xk[p];
        const unsigned* wrow = W1p + p * HIDDEN + wq * 16;  // wave-uniform
#pragma unroll
        for (int jj = 0; jj < 16; ++jj) h[jj] = dot2f(xp, wrow[jj], h[jj]);
    }

    // layer 2 partial: tanh, pack to f16 pairs, dot2 against pre-paired W2
    unsigned hp[8];
#pragma unroll
    for (int p = 0; p < 8; ++p)
        hp[p] = packh(fast_tanh(h[2 * p]), fast_tanh(h[2 * p + 1]));

    float o[2 + CCH];
#pragma unroll
    for (int k = 0; k < 2 + CCH; ++k) o[k] = 0.f;
#pragma unroll
    for (int p = 0; p < 8; ++p) {
        const unsigned* w2row = W2p + (wq * 8 + p) * 16;  // wave-uniform
#pragma unroll
        for (int k = 0; k < 2 + CCH; ++k) o[k] = dot2f(hp[p], w2row[k], o[k]);
    }

#pragma unroll
    for (int k = 0; k < 2 + CCH; ++k) part[wq][lane][k] = o[k];
    __syncthreads();

    // epilogue duties split by wave
    if (wq == 0) {
        float s0 = part[0][lane][0] + part[1][lane][0] + part[2][lane][0] + part[3][lane][0] + b2[0];
        float s1 = part[0][lane][1] + part[1][lane][1] + part[2][lane][1] + part[3][lane][1] + b2[1];
        float npx = px + s0 * DT;
        if (npx >= (float)GRIDN) npx -= (float)GRIDN;
        if (npx < 0.f) npx += (float)GRIDN;
        float npy = py + s1 * DT;
        if (npy >= (float)GRIDN) npy -= (float)GRIDN;
        if (npy < 0.f) npy += (float)GRIDN;
        out_pos[i] = npx;
        out_pos[i + NAGENTS] = npy;
        out_vel[i] = s0;
        out_vel[i + NAGENTS] = s1;
    } else if (wq == 1) {
        float d0 = part[0][lane][2] + part[1][lane][2] + part[2][lane][2] + part[3][lane][2] + b2[2];
        float d1 = part[0][lane][3] + part[1][lane][3] + part[2][lane][3] + part[3][lane][3] + b2[3];
        float d2 = part[0][lane][4] + part[1][lane][4] + part[2][lane][4] + part[3][lane][4] + b2[4];
        float d3 = part[0][lane][5] + part[1][lane][5] + part[2][lane][5] + part[3][lane][5] + b2[5];
        *(float4*)(dp + (size_t)i * CCH) = make_float4(d0, d1, d2, d3);
    } else if (wq == 2) {
        float d4 = part[0][lane][6] + part[1][lane][6] + part[2][lane][6] + part[3][lane][6] + b2[6];
        float d5 = part[0][lane][7] + part[1][lane][7] + part[2][lane][7] + part[3][lane][7] + b2[7];
        float d6 = part[0][lane][8] + part[1][lane][8] + part[2][lane][8] + part[3][lane][8] + b2[8];
        float d7 = part[0][lane][9] + part[1][lane][9] + part[2][lane][9] + part[3][lane][9] + b2[9];
        *(float4*)(dp + (size_t)i * CCH + 4) = make_float4(d4, d5, d6, d7);
    } else {
        int wx = (int)rintf(px) & (GRIDN - 1);
        int wy = (int)rintf(py) & (GRIDN - 1);
        atomicMax(&winner[(wx << 10) + wy], i);
    }
}

__device__ __forceinline__ void do_update(int vb, int tid,
                                          const float* __restrict__ lat,
                                          const int* __restrict__ winner,
                                          const float* __restrict__ dp,
                                          float* __restrict__ out_lat) {
    int idx = vb * 256 + tid;  // cell index
    int w = winner[idx];
    float d[CCH];
    if (w >= 0) {
        const float4* dpp = (const float4*)(dp + (size_t)w * CCH);
        float4 a = dpp[0], b = dpp[1];
        d[0] = a.x; d[1] = a.y; d[2] = a.z; d[3] = a.w;
        d[4] = b.x; d[5] = b.y; d[6] = b.z; d[7] = b.w;
    }
#pragma unroll
    for (int c = 0; c < CCH; ++c) {
        size_t off = (size_t)c * GRIDN * GRIDN + idx;
        float v = lat[off];
        if (w >= 0) v = fmaxf(v + DT * d[c], 0.f);
        out_lat[off] = v * DECAYF;
    }
}

// ---------------- fused cooperative kernel ----------------

__global__ void __launch_bounds__(256, 4) k_fused(
    const float* __restrict__ pos, const float* __restrict__ vel,
    const float* __restrict__ lat,
    const float* __restrict__ W1, const float* __restrict__ b1,
    const float* __restrict__ W2, const float* __restrict__ b2,
    float* __restrict__ out_pos, float* __restrict__ out_vel,
    float* __restrict__ out_lat,
    int* __restrict__ winner, float* __restrict__ dp,
    _Float16* __restrict__ BT, unsigned* __restrict__ W1p,
    unsigned* __restrict__ W2p) {
    __shared__ float part[4][64][13];
    int tid = threadIdx.x;
    int lane = tid & 63;
    int wq = __builtin_amdgcn_readfirstlane(tid >> 6);
    cg::grid_group grid = cg::this_grid();

    if (blockIdx.x == 0) do_pack(tid, W1, W2, W1p, W2p);
#pragma unroll 1
    for (int it = 0; it < NVB / NBLK; ++it)
        do_box(blockIdx.x + it * NBLK, tid, lat, BT, winner);

    grid.sync();

#pragma unroll 1
    for (int it = 0; it < NVB / NBLK; ++it) {
        do_agent(blockIdx.x + it * NBLK, lane, wq, part, pos, vel, BT,
                 W1p, b1, W2p, b2, out_pos, out_vel, dp, winner);
        __syncthreads();  // protect part[] reuse across iterations
    }

    grid.sync();

#pragma unroll 1
    for (int it = 0; it < NVB / NBLK; ++it)
        do_update(blockIdx.x + it * NBLK, tid, lat, winner, dp, out_lat);
}

// ---------------- fallback kernels (round-5 structure) ----------------

__global__ void __launch_bounds__(256) k_boxT(const float* __restrict__ lat,
                                              _Float16* __restrict__ BT,
                                              int* __restrict__ winner,
                                              const float* __restrict__ W1,
                                              const float* __restrict__ W2,
                                              unsigned* __restrict__ W1p,
                                              unsigned* __restrict__ W2p) {
    if (blockIdx.x == 0) do_pack(threadIdx.x, W1, W2, W1p, W2p);
    do_box(blockIdx.x, threadIdx.x, lat, BT, winner);
}

__global__ void __launch_bounds__(256) k_agent(
    const float* __restrict__ pos, const float* __restrict__ vel,
    const _Float16* __restrict__ BT,
    const unsigned* __restrict__ W1p, const float* __restrict__ b1,
    const unsigned* __restrict__ W2p, const float* __restrict__ b2,
    float* __restrict__ out_pos, float* __restrict__ out_vel,
    float* __restrict__ dp, int* __restrict__ winner) {
    __shared__ float part[4][64][13];
    int lane = threadIdx.x & 63;
    int wq = __builtin_amdgcn_readfirstlane(threadIdx.x >> 6);
    do_agent(blockIdx.x, lane, wq, part, pos, vel, BT, W1p, b1, W2p, b2,
             out_pos, out_vel, dp, winner);
}

__global__ void __launch_bounds__(256) k_update(const float* __restrict__ lat,
                                                const int* __restrict__ winner,
                                                const float* __restrict__ dp,
                                                float* __restrict__ out_lat) {
    do_update(blockIdx.x, threadIdx.x, lat, winner, dp, out_lat);
}

extern "C" void kernel_launch(void* const* d_in, const int* in_sizes, int n_in,
                              void* d_out, int out_size, void* d_ws, size_t ws_size,
                              hipStream_t stream) {
    const float* pos = (const float*)d_in[0];
    const float* vel = (const float*)d_in[1];
    const float* lat = (const float*)d_in[2];
    const float* W1  = (const float*)d_in[3];
    const float* b1  = (const float*)d_in[4];
    const float* W2  = (const float*)d_in[5];
    const float* b2  = (const float*)d_in[6];

    float* out      = (float*)d_out;
    float* out_pos  = out;                 // (2, N)
    float* out_vel  = out + 2 * NAGENTS;   // (2, N)
    float* out_lat  = out + 4 * NAGENTS;   // (C, G, G)

    char* ws = (char*)d_ws;
    int*       winner = (int*)ws;                       // 4 MB
    float*     dp     = (float*)(ws + (4 << 20));       // 8 MB
    _Float16*  BT     = (_Float16*)(ws + (12 << 20));   // 16 MB
    unsigned*  W1p    = (unsigned*)(ws + (28 << 20));   // 3 KB
    unsigned*  W2p    = (unsigned*)(ws + (28 << 20) + 4096);  // 2 KB

    void* args[] = {&pos, &vel, &lat, &W1, &b1, &W2, &b2,
                    &out_pos, &out_vel, &out_lat,
                    &winner, &dp, &BT, &W1p, &W2p};
    hipError_t e = hipLaunchCooperativeKernel((const void*)k_fused, dim3(NBLK),
                                              dim3(256), args, 0, stream);
    if (e != hipSuccess) {
        (void)hipGetLastError();  // clear sticky error, use 3-kernel fallback
        const int ncell = GRIDN * GRIDN;
        k_boxT<<<ncell / 256, 256, 0, stream>>>(lat, BT, winner, W1, W2, W1p, W2p);
        k_agent<<<NAGENTS / 64, 256, 0, stream>>>(pos, vel, BT, W1p, b1, W2p, b2,
                                                  out_pos, out_vel, dp, winner);
        k_update<<<ncell / 256, 256, 0, stream>>>(lat, winner, dp, out_lat);
    }
}

// Round 9
// 86.188 us; speedup vs baseline: 3.9184x; 3.9184x over previous
//
#include <hip/hip_runtime.h>
#include <math.h>

#define GRIDN 1024
#define NAGENTS 262144
#define CCH 8
#define HIDDEN 64
#define DT 0.1f
#define DECAYF 0.99f
#define SENSOR_LEN 3.0f
// cos(0.6), sin(0.6)
#define COS_SA 0.82533561490967829724f
#define SIN_SA 0.56464247339503535720f

typedef __attribute__((ext_vector_type(8))) short short8;
typedef __attribute__((ext_vector_type(2))) _Float16 half2v;

// packed 2-way f16 dot with f32 accumulate: v_dot2_f32_f16
__device__ __forceinline__ float dot2f(unsigned a, unsigned b, float c) {
#if __has_builtin(__builtin_amdgcn_fdot2)
    return __builtin_amdgcn_fdot2(__builtin_bit_cast(half2v, a),
                                  __builtin_bit_cast(half2v, b), c, false);
#else
    half2v ha = __builtin_bit_cast(half2v, a), hb = __builtin_bit_cast(half2v, b);
    return c + (float)ha.x * (float)hb.x + (float)ha.y * (float)hb.y;
#endif
}

__device__ __forceinline__ unsigned packh(float a, float b) {
    _Float16 ha = (_Float16)a, hb = (_Float16)b;
    unsigned short ua = __builtin_bit_cast(unsigned short, ha);
    unsigned short ub = __builtin_bit_cast(unsigned short, hb);
    return (unsigned)ua | ((unsigned)ub << 16);
}

// tanh(x) = (2^(2x*log2e) - 1) / (2^(2x*log2e) + 1), clamped so exp2 can't overflow
__device__ __forceinline__ float fast_tanh(float x) {
    float xc = fminf(fmaxf(x, -9.0f), 9.0f);
    float t = __builtin_amdgcn_exp2f(xc * 2.88539008177792681472f);  // 2*log2(e)
    return (t - 1.0f) * __builtin_amdgcn_rcpf(t + 1.0f);
}

// BT[x][y][c] = 3x3 torus box sum of channel c at (x,y), stored f16.
// Fused: winner init; block 0 packs weights into f16x2 pairs for dot2.
__global__ void __launch_bounds__(256) k_boxT(const float* __restrict__ lat,
                                              _Float16* __restrict__ BT,
                                              int* __restrict__ winner,
                                              const float* __restrict__ W1,
                                              const float* __restrict__ W2,
                                              unsigned* __restrict__ W1p,
                                              unsigned* __restrict__ W2p) {
    if (blockIdx.x == 0) {
        for (int t = threadIdx.x; t < 768 + 512; t += 256) {
            if (t < 768) {
                int p = t >> 6, j = t & 63;
                W1p[t] = packh(W1[(2 * p) * HIDDEN + j], W1[(2 * p + 1) * HIDDEN + j]);
            } else {
                int q = t - 768;
                int pg = q >> 4, k = q & 15;
                unsigned v = 0;
                if (k < 10) v = packh(W2[(2 * pg) * 10 + k], W2[(2 * pg + 1) * 10 + k]);
                W2p[q] = v;
            }
        }
    }
    int idx = blockIdx.x * blockDim.x + threadIdx.x;  // 0 .. 1M-1
    winner[idx] = -1;
    int x = idx >> 10, y = idx & (GRIDN - 1);
    int xm = (x + GRIDN - 1) & (GRIDN - 1), xp = (x + 1) & (GRIDN - 1);
    int ym = (y + GRIDN - 1) & (GRIDN - 1), yp = (y + 1) & (GRIDN - 1);
    _Float16 out[CCH];
#pragma unroll
    for (int c = 0; c < CCH; ++c) {
        const float* L = lat + (size_t)c * GRIDN * GRIDN;
        const float* r0 = L + xm * GRIDN;
        const float* r1 = L + x * GRIDN;
        const float* r2 = L + xp * GRIDN;
        float s = r0[ym] + r0[y] + r0[yp]
                + r1[ym] + r1[y] + r1[yp]
                + r2[ym] + r2[y] + r2[yp];
        out[c] = (_Float16)s;
    }
    *(short8*)(BT + (size_t)idx * CCH) = *(const short8*)out;
}

// 1 thread = 1 agent. Coalesced pos/vel loads -> tiny dir math -> 3 scattered
// 16B gathers -> coalesced 48B store of the sensed vector. No MLP in the
// dependency chain: gather latency is hidden purely by wave TLP (4096 cheap
// waves). Winner atomicMax fused here (pos already in registers).
__global__ void __launch_bounds__(256) k_sense(const float* __restrict__ pos,
                                               const float* __restrict__ vel,
                                               const _Float16* __restrict__ BT,
                                               uint4* __restrict__ XK,
                                               int* __restrict__ winner) {
    int i = blockIdx.x * blockDim.x + threadIdx.x;
    float px = pos[i], py = pos[i + NAGENTS];
    float vx = vel[i], vy = vel[i + NAGENTS];

    float r2 = vx * vx + vy * vy;
    float ct, st;
    if (r2 > 0.f) {
        float inv = rsqrtf(r2);
        ct = vx * inv;
        st = vy * inv;
    } else {
        ct = 1.f;  // atan2(0,0) = 0
        st = 0.f;
    }

    float dirx[3], diry[3];
    dirx[0] = ct;                          diry[0] = st;
    dirx[1] = ct * COS_SA - st * SIN_SA;   diry[1] = st * COS_SA + ct * SIN_SA;
    dirx[2] = ct * COS_SA + st * SIN_SA;   diry[2] = st * COS_SA - ct * SIN_SA;

#pragma unroll
    for (int s = 0; s < 3; ++s) {
        int gx = ((int)rintf(px + SENSOR_LEN * dirx[s]) + GRIDN) & (GRIDN - 1);
        int gy = ((int)rintf(py + SENSOR_LEN * diry[s]) + GRIDN) & (GRIDN - 1);
        XK[(size_t)i * 3 + s] = *(const uint4*)(BT + ((size_t)(gx << 10) + gy) * CCH);
    }

    int wx = (int)rintf(px) & (GRIDN - 1);
    int wy = (int)rintf(py) & (GRIDN - 1);
    atomicMax(&winner[(wx << 10) + wy], i);
}

// 1 thread = 1 agent, FULL hidden layer per thread. All loads coalesced
// (XK 48B/agent) or wave-uniform SGPR (weights). Zero scattered access,
// no LDS, no divergence: pure VALU-dense kernel.
__global__ void __launch_bounds__(256) k_mlp(
    const float* __restrict__ pos,
    const uint4* __restrict__ XK,
    const unsigned* __restrict__ W1p, const float* __restrict__ b1,
    const unsigned* __restrict__ W2p, const float* __restrict__ b2,
    float* __restrict__ out_pos, float* __restrict__ out_vel,
    float* __restrict__ dp) {
    int i = blockIdx.x * blockDim.x + threadIdx.x;

    uint4 g0 = XK[(size_t)i * 3 + 0];
    uint4 g1 = XK[(size_t)i * 3 + 1];
    uint4 g2 = XK[(size_t)i * 3 + 2];
    unsigned xk[12] = {g0.x, g0.y, g0.z, g0.w,
                       g1.x, g1.y, g1.z, g1.w,
                       g2.x, g2.y, g2.z, g2.w};

    // layer 1: h[j] = b1[j] + sum_p dot2(xk[p], W1p[p][j])
    float h[HIDDEN];
#pragma unroll
    for (int j = 0; j < HIDDEN; ++j) h[j] = b1[j];
#pragma unroll
    for (int p = 0; p < 12; ++p) {
        unsigned xp = xk[p];
        const unsigned* wrow = W1p + p * HIDDEN;  // wave-uniform -> SGPR
#pragma unroll
        for (int j = 0; j < HIDDEN; ++j) h[j] = dot2f(xp, wrow[j], h[j]);
    }

    // layer 2: o = tanh(h) @ W2 + b2, packed f16 pairs
    float o[2 + CCH];
#pragma unroll
    for (int k = 0; k < 2 + CCH; ++k) o[k] = b2[k];
#pragma unroll
    for (int p = 0; p < 32; ++p) {
        unsigned hp = packh(fast_tanh(h[2 * p]), fast_tanh(h[2 * p + 1]));
        const unsigned* w2row = W2p + p * 16;  // wave-uniform -> SGPR
#pragma unroll
        for (int k = 0; k < 2 + CCH; ++k) o[k] = dot2f(hp, w2row[k], o[k]);
    }

    float px = pos[i], py = pos[i + NAGENTS];
    float nvx = o[0], nvy = o[1];
    // pos in [2,1022], |vel*DT| tiny -> at most one wrap either side
    float npx = px + nvx * DT;
    if (npx >= (float)GRIDN) npx -= (float)GRIDN;
    if (npx < 0.f) npx += (float)GRIDN;
    float npy = py + nvy * DT;
    if (npy >= (float)GRIDN) npy -= (float)GRIDN;
    if (npy < 0.f) npy += (float)GRIDN;

    out_pos[i] = npx;
    out_pos[i + NAGENTS] = npy;
    out_vel[i] = nvx;
    out_vel[i + NAGENTS] = nvy;

    float4* dpp = (float4*)(dp + (size_t)i * CCH);
    dpp[0] = make_float4(o[2], o[3], o[4], o[5]);
    dpp[1] = make_float4(o[6], o[7], o[8], o[9]);
}

__global__ void __launch_bounds__(256) k_update(const float* __restrict__ lat,
                                                const int* __restrict__ winner,
                                                const float* __restrict__ dp,
                                                float* __restrict__ out_lat) {
    int idx = blockIdx.x * blockDim.x + threadIdx.x;  // cell index
    int w = winner[idx];
    float d[CCH];
    if (w >= 0) {
        const float4* dpp = (const float4*)(dp + (size_t)w * CCH);
        float4 a = dpp[0], b = dpp[1];
        d[0] = a.x; d[1] = a.y; d[2] = a.z; d[3] = a.w;
        d[4] = b.x; d[5] = b.y; d[6] = b.z; d[7] = b.w;
    }
#pragma unroll
    for (int c = 0; c < CCH; ++c) {
        size_t off = (size_t)c * GRIDN * GRIDN + idx;
        float v = lat[off];
        if (w >= 0) v = fmaxf(v + DT * d[c], 0.f);
        out_lat[off] = v * DECAYF;
    }
}

extern "C" void kernel_launch(void* const* d_in, const int* in_sizes, int n_in,
                              void* d_out, int out_size, void* d_ws, size_t ws_size,
                              hipStream_t stream) {
    const float* pos = (const float*)d_in[0];
    const float* vel = (const float*)d_in[1];
    const float* lat = (const float*)d_in[2];
    const float* W1  = (const float*)d_in[3];
    const float* b1  = (const float*)d_in[4];
    const float* W2  = (const float*)d_in[5];
    const float* b2  = (const float*)d_in[6];

    float* out      = (float*)d_out;
    float* out_pos  = out;                 // (2, N)
    float* out_vel  = out + 2 * NAGENTS;   // (2, N)
    float* out_lat  = out + 4 * NAGENTS;   // (C, G, G)

    char* ws = (char*)d_ws;
    int*       winner = (int*)ws;                            // 4 MB
    float*     dp     = (float*)(ws + (4 << 20));            // 8 MB
    _Float16*  BT     = (_Float16*)(ws + (12 << 20));        // 16 MB
    unsigned*  W1p    = (unsigned*)(ws + (28 << 20));        // 3 KB
    unsigned*  W2p    = (unsigned*)(ws + (28 << 20) + 4096); // 2 KB
    uint4*     XK     = (uint4*)(ws + (29 << 20));           // 12 MB

    const int ncell = GRIDN * GRIDN;

    k_boxT<<<ncell / 256, 256, 0, stream>>>(lat, BT, winner, W1, W2, W1p, W2p);
    k_sense<<<NAGENTS / 256, 256, 0, stream>>>(pos, vel, BT, XK, winner);
    k_mlp<<<NAGENTS / 256, 256, 0, stream>>>(pos, XK, W1p, b1, W2p, b2,
                                             out_pos, out_vel, dp);
    k_update<<<ncell / 256, 256, 0, stream>>>(lat, winner, dp, out_lat);
}

// Round 10
// 77.330 us; speedup vs baseline: 4.3673x; 1.1146x over previous
//
#include <hip/hip_runtime.h>
#include <math.h>

#define GRIDN 1024
#define NAGENTS 262144
#define CCH 8
#define HIDDEN 64
#define DT 0.1f
#define DECAYF 0.99f
#define SENSOR_LEN 3.0f
// cos(0.6), sin(0.6)
#define COS_SA 0.82533561490967829724f
#define SIN_SA 0.56464247339503535720f

typedef __attribute__((ext_vector_type(8))) short short8;
typedef __attribute__((ext_vector_type(2))) _Float16 half2v;

// packed 2-way f16 dot with f32 accumulate: v_dot2_f32_f16
__device__ __forceinline__ float dot2f(unsigned a, unsigned b, float c) {
#if __has_builtin(__builtin_amdgcn_fdot2)
    return __builtin_amdgcn_fdot2(__builtin_bit_cast(half2v, a),
                                  __builtin_bit_cast(half2v, b), c, false);
#else
    half2v ha = __builtin_bit_cast(half2v, a), hb = __builtin_bit_cast(half2v, b);
    return c + (float)ha.x * (float)hb.x + (float)ha.y * (float)hb.y;
#endif
}

__device__ __forceinline__ unsigned packh(float a, float b) {
    _Float16 ha = (_Float16)a, hb = (_Float16)b;
    unsigned short ua = __builtin_bit_cast(unsigned short, ha);
    unsigned short ub = __builtin_bit_cast(unsigned short, hb);
    return (unsigned)ua | ((unsigned)ub << 16);
}

// tanh(x) = (2^(2x*log2e) - 1) / (2^(2x*log2e) + 1), clamped so exp2 can't overflow
__device__ __forceinline__ float fast_tanh(float x) {
    float xc = fminf(fmaxf(x, -9.0f), 9.0f);
    float t = __builtin_amdgcn_exp2f(xc * 2.88539008177792681472f);  // 2*log2(e)
    return (t - 1.0f) * __builtin_amdgcn_rcpf(t + 1.0f);
}

// BT[x][y][c] = 3x3 torus box sum of channel c at (x,y), stored f16.
// Fused: winner init; block 0 packs weights into f16x2 pairs for dot2.
__global__ void __launch_bounds__(256) k_boxT(const float* __restrict__ lat,
                                              _Float16* __restrict__ BT,
                                              int* __restrict__ winner,
                                              const float* __restrict__ W1,
                                              const float* __restrict__ W2,
                                              unsigned* __restrict__ W1p,
                                              unsigned* __restrict__ W2p) {
    if (blockIdx.x == 0) {
        for (int t = threadIdx.x; t < 768 + 512; t += 256) {
            if (t < 768) {
                int p = t >> 6, j = t & 63;
                W1p[t] = packh(W1[(2 * p) * HIDDEN + j], W1[(2 * p + 1) * HIDDEN + j]);
            } else {
                int q = t - 768;
                int pg = q >> 4, k = q & 15;
                unsigned v = 0;
                if (k < 10) v = packh(W2[(2 * pg) * 10 + k], W2[(2 * pg + 1) * 10 + k]);
                W2p[q] = v;
            }
        }
    }
    int idx = blockIdx.x * blockDim.x + threadIdx.x;  // 0 .. 1M-1
    winner[idx] = -1;
    int x = idx >> 10, y = idx & (GRIDN - 1);
    int xm = (x + GRIDN - 1) & (GRIDN - 1), xp = (x + 1) & (GRIDN - 1);
    int ym = (y + GRIDN - 1) & (GRIDN - 1), yp = (y + 1) & (GRIDN - 1);
    _Float16 out[CCH];
#pragma unroll
    for (int c = 0; c < CCH; ++c) {
        const float* L = lat + (size_t)c * GRIDN * GRIDN;
        const float* r0 = L + xm * GRIDN;
        const float* r1 = L + x * GRIDN;
        const float* r2 = L + xp * GRIDN;
        float s = r0[ym] + r0[y] + r0[yp]
                + r1[ym] + r1[y] + r1[yp]
                + r2[ym] + r2[y] + r2[yp];
        out[c] = (_Float16)s;
    }
    *(short8*)(BT + (size_t)idx * CCH) = *(const short8*)out;
}

// Round-5 structure, grid DOUBLED for counter visibility: blocks bid and
// bid+4096 compute the same 64 agents and write byte-identical results
// (benign duplicate writes; atomicMax idempotent). This lifts the kernel
// above the harness's 40us fillBuffer dispatches so rocprof's top-5 shows
// its VALUBusy / Occupancy / FETCH_SIZE / LDS_BANK_CONFLICT.
__global__ void __launch_bounds__(256) k_agent(
    const float* __restrict__ pos, const float* __restrict__ vel,
    const _Float16* __restrict__ BT,
    const unsigned* __restrict__ W1p, const float* __restrict__ b1,
    const unsigned* __restrict__ W2p, const float* __restrict__ b2,
    float* __restrict__ out_pos, float* __restrict__ out_vel,
    float* __restrict__ dp, int* __restrict__ winner) {
    __shared__ float part[4][64][13];  // 13-pad: stride coprime with 32 banks

    int lane = threadIdx.x & 63;
    int wq = __builtin_amdgcn_readfirstlane(threadIdx.x >> 6);  // SGPR slice id
    int vb = blockIdx.x & 4095;  // duplicate pass: identical work + writes
    int i = vb * 64 + lane;      // agent

    float px = pos[i], py = pos[i + NAGENTS];
    float vx = vel[i], vy = vel[i + NAGENTS];

    float r2 = vx * vx + vy * vy;
    float ct, st;
    if (r2 > 0.f) {
        float inv = rsqrtf(r2);
        ct = vx * inv;
        st = vy * inv;
    } else {
        ct = 1.f;  // atan2(0,0) = 0
        st = 0.f;
    }

    // sensor directions: front, +0.6 (left), -0.6 (right)
    float dirx[3], diry[3];
    dirx[0] = ct;                          diry[0] = st;
    dirx[1] = ct * COS_SA - st * SIN_SA;   diry[1] = st * COS_SA + ct * SIN_SA;
    dirx[2] = ct * COS_SA + st * SIN_SA;   diry[2] = st * COS_SA - ct * SIN_SA;

    uint4 raw[3];
#pragma unroll
    for (int s = 0; s < 3; ++s) {
        int gx = ((int)rintf(px + SENSOR_LEN * dirx[s]) + GRIDN) & (GRIDN - 1);
        int gy = ((int)rintf(py + SENSOR_LEN * diry[s]) + GRIDN) & (GRIDN - 1);
        raw[s] = *(const uint4*)(BT + ((size_t)(gx << 10) + gy) * CCH);
    }
    // xk[p] = f16 pair (x[2p], x[2p+1]); x = [front8, left8, right8]
    unsigned xk[12];
#pragma unroll
    for (int s = 0; s < 3; ++s) {
        xk[s * 4 + 0] = raw[s].x; xk[s * 4 + 1] = raw[s].y;
        xk[s * 4 + 2] = raw[s].z; xk[s * 4 + 3] = raw[s].w;
    }

    // layer 1: h[jj] = b1[wq*16+jj] + sum_p dot2(xk[p], W1pair[p][wq*16+jj])
    float h[16];
    {
        const float4* b1v = (const float4*)(b1 + wq * 16);
#pragma unroll
        for (int q = 0; q < 4; ++q) {
            float4 b = b1v[q];
            h[q * 4 + 0] = b.x; h[q * 4 + 1] = b.y;
            h[q * 4 + 2] = b.z; h[q * 4 + 3] = b.w;
        }
    }
#pragma unroll
    for (int p = 0; p < 12; ++p) {
        unsigned xp = xk[p];
        const unsigned* wrow = W1p + p * HIDDEN + wq * 16;  // wave-uniform
#pragma unroll
        for (int jj = 0; jj < 16; ++jj) h[jj] = dot2f(xp, wrow[jj], h[jj]);
    }

    // layer 2 partial: tanh, pack to f16 pairs, dot2 against pre-paired W2
    unsigned hp[8];
#pragma unroll
    for (int p = 0; p < 8; ++p)
        hp[p] = packh(fast_tanh(h[2 * p]), fast_tanh(h[2 * p + 1]));

    float o[2 + CCH];
#pragma unroll
    for (int k = 0; k < 2 + CCH; ++k) o[k] = 0.f;
#pragma unroll
    for (int p = 0; p < 8; ++p) {
        const unsigned* w2row = W2p + (wq * 8 + p) * 16;  // wave-uniform
#pragma unroll
        for (int k = 0; k < 2 + CCH; ++k) o[k] = dot2f(hp[p], w2row[k], o[k]);
    }

#pragma unroll
    for (int k = 0; k < 2 + CCH; ++k) part[wq][lane][k] = o[k];
    __syncthreads();

    // epilogue duties split by wave
    if (wq == 0) {
        float s0 = part[0][lane][0] + part[1][lane][0] + part[2][lane][0] + part[3][lane][0] + b2[0];
        float s1 = part[0][lane][1] + part[1][lane][1] + part[2][lane][1] + part[3][lane][1] + b2[1];
        float npx = px + s0 * DT;
        if (npx >= (float)GRIDN) npx -= (float)GRIDN;
        if (npx < 0.f) npx += (float)GRIDN;
        float npy = py + s1 * DT;
        if (npy >= (float)GRIDN) npy -= (float)GRIDN;
        if (npy < 0.f) npy += (float)GRIDN;
        out_pos[i] = npx;
        out_pos[i + NAGENTS] = npy;
        out_vel[i] = s0;
        out_vel[i + NAGENTS] = s1;
    } else if (wq == 1) {
        float d0 = part[0][lane][2] + part[1][lane][2] + part[2][lane][2] + part[3][lane][2] + b2[2];
        float d1 = part[0][lane][3] + part[1][lane][3] + part[2][lane][3] + part[3][lane][3] + b2[3];
        float d2 = part[0][lane][4] + part[1][lane][4] + part[2][lane][4] + part[3][lane][4] + b2[4];
        float d3 = part[0][lane][5] + part[1][lane][5] + part[2][lane][5] + part[3][lane][5] + b2[5];
        *(float4*)(dp + (size_t)i * CCH) = make_float4(d0, d1, d2, d3);
    } else if (wq == 2) {
        float d4 = part[0][lane][6] + part[1][lane][6] + part[2][lane][6] + part[3][lane][6] + b2[6];
        float d5 = part[0][lane][7] + part[1][lane][7] + part[2][lane][7] + part[3][lane][7] + b2[7];
        float d6 = part[0][lane][8] + part[1][lane][8] + part[2][lane][8] + part[3][lane][8] + b2[8];
        float d7 = part[0][lane][9] + part[1][lane][9] + part[2][lane][9] + part[3][lane][9] + b2[9];
        *(float4*)(dp + (size_t)i * CCH + 4) = make_float4(d4, d5, d6, d7);
    } else {
        int wx = (int)rintf(px) & (GRIDN - 1);
        int wy = (int)rintf(py) & (GRIDN - 1);
        atomicMax(&winner[(wx << 10) + wy], i);
    }
}

__global__ void __launch_bounds__(256) k_update(const float* __restrict__ lat,
                                                const int* __restrict__ winner,
                                                const float* __restrict__ dp,
                                                float* __restrict__ out_lat) {
    int idx = blockIdx.x * blockDim.x + threadIdx.x;  // cell index
    int w = winner[idx];
    float d[CCH];
    if (w >= 0) {
        const float4* dpp = (const float4*)(dp + (size_t)w * CCH);
        float4 a = dpp[0], b = dpp[1];
        d[0] = a.x; d[1] = a.y; d[2] = a.z; d[3] = a.w;
        d[4] = b.x; d[5] = b.y; d[6] = b.z; d[7] = b.w;
    }
#pragma unroll
    for (int c = 0; c < CCH; ++c) {
        size_t off = (size_t)c * GRIDN * GRIDN + idx;
        float v = lat[off];
        if (w >= 0) v = fmaxf(v + DT * d[c], 0.f);
        out_lat[off] = v * DECAYF;
    }
}

extern "C" void kernel_launch(void* const* d_in, const int* in_sizes, int n_in,
                              void* d_out, int out_size, void* d_ws, size_t ws_size,
                              hipStream_t stream) {
    const float* pos = (const float*)d_in[0];
    const float* vel = (const float*)d_in[1];
    const float* lat = (const float*)d_in[2];
    const float* W1  = (const float*)d_in[3];
    const float* b1  = (const float*)d_in[4];
    const float* W2  = (const float*)d_in[5];
    const float* b2  = (const float*)d_in[6];

    float* out      = (float*)d_out;
    float* out_pos  = out;                 // (2, N)
    float* out_vel  = out + 2 * NAGENTS;   // (2, N)
    float* out_lat  = out + 4 * NAGENTS;   // (C, G, G)

    char* ws = (char*)d_ws;
    int*       winner = (int*)ws;                            // 4 MB
    float*     dp     = (float*)(ws + (4 << 20));            // 8 MB
    _Float16*  BT     = (_Float16*)(ws + (12 << 20));        // 16 MB
    unsigned*  W1p    = (unsigned*)(ws + (28 << 20));        // 3 KB
    unsigned*  W2p    = (unsigned*)(ws + (28 << 20) + 4096); // 2 KB

    const int ncell = GRIDN * GRIDN;

    k_boxT<<<ncell / 256, 256, 0, stream>>>(lat, BT, winner, W1, W2, W1p, W2p);
    // grid x2: duplicate pass for rocprof visibility (identical writes)
    k_agent<<<NAGENTS / 64 * 2, 256, 0, stream>>>(pos, vel, BT, W1p, b1, W2p, b2,
                                                  out_pos, out_vel, dp, winner);
    k_update<<<ncell / 256, 256, 0, stream>>>(lat, winner, dp, out_lat);
}

// Round 11
// 63.009 us; speedup vs baseline: 5.3599x; 1.2273x over previous
//
#include <hip/hip_runtime.h>
#include <math.h>

#define GRIDN 1024
#define NAGENTS 262144
#define CCH 8
#define HIDDEN 64
#define DT 0.1f
#define DECAYF 0.99f
#define SENSOR_LEN 3.0f
// cos(0.6), sin(0.6)
#define COS_SA 0.82533561490967829724f
#define SIN_SA 0.56464247339503535720f

typedef __attribute__((ext_vector_type(8))) short short8;
typedef __attribute__((ext_vector_type(2))) _Float16 half2v;

// packed 2-way f16 dot with f32 accumulate: v_dot2_f32_f16
__device__ __forceinline__ float dot2f(unsigned a, unsigned b, float c) {
#if __has_builtin(__builtin_amdgcn_fdot2)
    return __builtin_amdgcn_fdot2(__builtin_bit_cast(half2v, a),
                                  __builtin_bit_cast(half2v, b), c, false);
#else
    half2v ha = __builtin_bit_cast(half2v, a), hb = __builtin_bit_cast(half2v, b);
    return c + (float)ha.x * (float)hb.x + (float)ha.y * (float)hb.y;
#endif
}

__device__ __forceinline__ unsigned packh(float a, float b) {
    _Float16 ha = (_Float16)a, hb = (_Float16)b;
    unsigned short ua = __builtin_bit_cast(unsigned short, ha);
    unsigned short ub = __builtin_bit_cast(unsigned short, hb);
    return (unsigned)ua | ((unsigned)ub << 16);
}

// tanh(x) = (2^(2x*log2e) - 1) / (2^(2x*log2e) + 1), clamped so exp2 can't overflow
__device__ __forceinline__ float fast_tanh(float x) {
    float xc = fminf(fmaxf(x, -9.0f), 9.0f);
    float t = __builtin_amdgcn_exp2f(xc * 2.88539008177792681472f);  // 2*log2(e)
    return (t - 1.0f) * __builtin_amdgcn_rcpf(t + 1.0f);
}

// BT[x][y][c] = 3x3 torus box sum of channel c at (x,y), stored f16.
// Fused: winner init; block 0 packs weights into f16x2 pairs for dot2.
__global__ void __launch_bounds__(256) k_boxT(const float* __restrict__ lat,
                                              _Float16* __restrict__ BT,
                                              int* __restrict__ winner,
                                              const float* __restrict__ W1,
                                              const float* __restrict__ W2,
                                              unsigned* __restrict__ W1p,
                                              unsigned* __restrict__ W2p) {
    if (blockIdx.x == 0) {
        for (int t = threadIdx.x; t < 768 + 512; t += 256) {
            if (t < 768) {
                int p = t >> 6, j = t & 63;
                W1p[t] = packh(W1[(2 * p) * HIDDEN + j], W1[(2 * p + 1) * HIDDEN + j]);
            } else {
                int q = t - 768;
                int pg = q >> 4, k = q & 15;
                unsigned v = 0;
                if (k < 10) v = packh(W2[(2 * pg) * 10 + k], W2[(2 * pg + 1) * 10 + k]);
                W2p[q] = v;
            }
        }
    }
    int idx = blockIdx.x * blockDim.x + threadIdx.x;  // 0 .. 1M-1
    winner[idx] = -1;
    int x = idx >> 10, y = idx & (GRIDN - 1);
    int xm = (x + GRIDN - 1) & (GRIDN - 1), xp = (x + 1) & (GRIDN - 1);
    int ym = (y + GRIDN - 1) & (GRIDN - 1), yp = (y + 1) & (GRIDN - 1);
    _Float16 out[CCH];
#pragma unroll
    for (int c = 0; c < CCH; ++c) {
        const float* L = lat + (size_t)c * GRIDN * GRIDN;
        const float* r0 = L + xm * GRIDN;
        const float* r1 = L + x * GRIDN;
        const float* r2 = L + xp * GRIDN;
        float s = r0[ym] + r0[y] + r0[yp]
                + r1[ym] + r1[y] + r1[yp]
                + r2[ym] + r2[y] + r2[yp];
        out[c] = (_Float16)s;
    }
    *(short8*)(BT + (size_t)idx * CCH) = *(const short8*)out;
}

// Round-5 structure + 2-agent ILP: block = 4 waves = 128 agents; each thread
// handles agents iA = blk*128+lane and iB = iA+64 with fully independent
// instruction streams (all 6 gathers issued before either MLP consumes).
// Wave wq owns hidden slice [wq*16,+16) for both agents (SGPR-uniform weights).
__global__ void __launch_bounds__(256) k_agent(
    const float* __restrict__ pos, const float* __restrict__ vel,
    const _Float16* __restrict__ BT,
    const unsigned* __restrict__ W1p, const float* __restrict__ b1,
    const unsigned* __restrict__ W2p, const float* __restrict__ b2,
    float* __restrict__ out_pos, float* __restrict__ out_vel,
    float* __restrict__ dp, int* __restrict__ winner) {
    __shared__ float part[4][128][13];  // 13-pad: stride coprime with 32 banks

    int lane = threadIdx.x & 63;
    int wq = __builtin_amdgcn_readfirstlane(threadIdx.x >> 6);  // SGPR slice id
    int iA = blockIdx.x * 128 + lane;  // agent A
    int iB = iA + 64;                  // agent B

    float pxA = pos[iA], pyA = pos[iA + NAGENTS];
    float vxA = vel[iA], vyA = vel[iA + NAGENTS];
    float pxB = pos[iB], pyB = pos[iB + NAGENTS];
    float vxB = vel[iB], vyB = vel[iB + NAGENTS];

    // ---- sense both agents: issue all 6 gathers up front ----
    uint4 rawA[3], rawB[3];
#pragma unroll
    for (int a = 0; a < 2; ++a) {
        float px = a ? pxB : pxA, py = a ? pyB : pyA;
        float vx = a ? vxB : vxA, vy = a ? vyB : vyA;
        float r2 = vx * vx + vy * vy;
        float ct, st;
        if (r2 > 0.f) {
            float inv = rsqrtf(r2);
            ct = vx * inv;
            st = vy * inv;
        } else {
            ct = 1.f;  // atan2(0,0) = 0
            st = 0.f;
        }
        float dirx[3], diry[3];
        dirx[0] = ct;                          diry[0] = st;
        dirx[1] = ct * COS_SA - st * SIN_SA;   diry[1] = st * COS_SA + ct * SIN_SA;
        dirx[2] = ct * COS_SA + st * SIN_SA;   diry[2] = st * COS_SA - ct * SIN_SA;
        uint4* raw = a ? rawB : rawA;
#pragma unroll
        for (int s = 0; s < 3; ++s) {
            int gx = ((int)rintf(px + SENSOR_LEN * dirx[s]) + GRIDN) & (GRIDN - 1);
            int gy = ((int)rintf(py + SENSOR_LEN * diry[s]) + GRIDN) & (GRIDN - 1);
            raw[s] = *(const uint4*)(BT + ((size_t)(gx << 10) + gy) * CCH);
        }
    }

    unsigned xkA[12] = {rawA[0].x, rawA[0].y, rawA[0].z, rawA[0].w,
                        rawA[1].x, rawA[1].y, rawA[1].z, rawA[1].w,
                        rawA[2].x, rawA[2].y, rawA[2].z, rawA[2].w};
    unsigned xkB[12] = {rawB[0].x, rawB[0].y, rawB[0].z, rawB[0].w,
                        rawB[1].x, rawB[1].y, rawB[1].z, rawB[1].w,
                        rawB[2].x, rawB[2].y, rawB[2].z, rawB[2].w};

    // ---- layer 1 for both agents (shared SGPR weight stream, 2x ILP) ----
    float hA[16], hB[16];
    {
        const float4* b1v = (const float4*)(b1 + wq * 16);
#pragma unroll
        for (int q = 0; q < 4; ++q) {
            float4 b = b1v[q];
            hA[q * 4 + 0] = b.x; hA[q * 4 + 1] = b.y;
            hA[q * 4 + 2] = b.z; hA[q * 4 + 3] = b.w;
            hB[q * 4 + 0] = b.x; hB[q * 4 + 1] = b.y;
            hB[q * 4 + 2] = b.z; hB[q * 4 + 3] = b.w;
        }
    }
#pragma unroll
    for (int p = 0; p < 12; ++p) {
        unsigned xpA = xkA[p], xpB = xkB[p];
        const unsigned* wrow = W1p + p * HIDDEN + wq * 16;  // wave-uniform
#pragma unroll
        for (int jj = 0; jj < 16; ++jj) {
            unsigned w = wrow[jj];
            hA[jj] = dot2f(xpA, w, hA[jj]);
            hB[jj] = dot2f(xpB, w, hB[jj]);
        }
    }

    // ---- layer 2 partials for both agents ----
    unsigned hpA[8], hpB[8];
#pragma unroll
    for (int p = 0; p < 8; ++p) {
        hpA[p] = packh(fast_tanh(hA[2 * p]), fast_tanh(hA[2 * p + 1]));
        hpB[p] = packh(fast_tanh(hB[2 * p]), fast_tanh(hB[2 * p + 1]));
    }

    float oA[2 + CCH], oB[2 + CCH];
#pragma unroll
    for (int k = 0; k < 2 + CCH; ++k) { oA[k] = 0.f; oB[k] = 0.f; }
#pragma unroll
    for (int p = 0; p < 8; ++p) {
        const unsigned* w2row = W2p + (wq * 8 + p) * 16;  // wave-uniform
#pragma unroll
        for (int k = 0; k < 2 + CCH; ++k) {
            unsigned w = w2row[k];
            oA[k] = dot2f(hpA[p], w, oA[k]);
            oB[k] = dot2f(hpB[p], w, oB[k]);
        }
    }

#pragma unroll
    for (int k = 0; k < 2 + CCH; ++k) {
        part[wq][lane][k] = oA[k];
        part[wq][lane + 64][k] = oB[k];
    }
    __syncthreads();

    // ---- epilogue duties split by wave, both agents ----
    if (wq == 0) {
#pragma unroll
        for (int a = 0; a < 2; ++a) {
            int i = a ? iB : iA;
            int ln = lane + a * 64;
            float px = a ? pxB : pxA, py = a ? pyB : pyA;
            float s0 = part[0][ln][0] + part[1][ln][0] + part[2][ln][0] + part[3][ln][0] + b2[0];
            float s1 = part[0][ln][1] + part[1][ln][1] + part[2][ln][1] + part[3][ln][1] + b2[1];
            float npx = px + s0 * DT;
            if (npx >= (float)GRIDN) npx -= (float)GRIDN;
            if (npx < 0.f) npx += (float)GRIDN;
            float npy = py + s1 * DT;
            if (npy >= (float)GRIDN) npy -= (float)GRIDN;
            if (npy < 0.f) npy += (float)GRIDN;
            out_pos[i] = npx;
            out_pos[i + NAGENTS] = npy;
            out_vel[i] = s0;
            out_vel[i + NAGENTS] = s1;
        }
    } else if (wq == 1) {
#pragma unroll
        for (int a = 0; a < 2; ++a) {
            int i = a ? iB : iA;
            int ln = lane + a * 64;
            float d0 = part[0][ln][2] + part[1][ln][2] + part[2][ln][2] + part[3][ln][2] + b2[2];
            float d1 = part[0][ln][3] + part[1][ln][3] + part[2][ln][3] + part[3][ln][3] + b2[3];
            float d2 = part[0][ln][4] + part[1][ln][4] + part[2][ln][4] + part[3][ln][4] + b2[4];
            float d3 = part[0][ln][5] + part[1][ln][5] + part[2][ln][5] + part[3][ln][5] + b2[5];
            *(float4*)(dp + (size_t)i * CCH) = make_float4(d0, d1, d2, d3);
        }
    } else if (wq == 2) {
#pragma unroll
        for (int a = 0; a < 2; ++a) {
            int i = a ? iB : iA;
            int ln = lane + a * 64;
            float d4 = part[0][ln][6] + part[1][ln][6] + part[2][ln][6] + part[3][ln][6] + b2[6];
            float d5 = part[0][ln][7] + part[1][ln][7] + part[2][ln][7] + part[3][ln][7] + b2[7];
            float d6 = part[0][ln][8] + part[1][ln][8] + part[2][ln][8] + part[3][ln][8] + b2[8];
            float d7 = part[0][ln][9] + part[1][ln][9] + part[2][ln][9] + part[3][ln][9] + b2[9];
            *(float4*)(dp + (size_t)i * CCH + 4) = make_float4(d4, d5, d6, d7);
        }
    } else {
        int wxA = (int)rintf(pxA) & (GRIDN - 1);
        int wyA = (int)rintf(pyA) & (GRIDN - 1);
        atomicMax(&winner[(wxA << 10) + wyA], iA);
        int wxB = (int)rintf(pxB) & (GRIDN - 1);
        int wyB = (int)rintf(pyB) & (GRIDN - 1);
        atomicMax(&winner[(wxB << 10) + wyB], iB);
    }
}

__global__ void __launch_bounds__(256) k_update(const float* __restrict__ lat,
                                                const int* __restrict__ winner,
                                                const float* __restrict__ dp,
                                                float* __restrict__ out_lat) {
    int idx = blockIdx.x * blockDim.x + threadIdx.x;  // cell index
    int w = winner[idx];
    float d[CCH];
    if (w >= 0) {
        const float4* dpp = (const float4*)(dp + (size_t)w * CCH);
        float4 a = dpp[0], b = dpp[1];
        d[0] = a.x; d[1] = a.y; d[2] = a.z; d[3] = a.w;
        d[4] = b.x; d[5] = b.y; d[6] = b.z; d[7] = b.w;
    }
#pragma unroll
    for (int c = 0; c < CCH; ++c) {
        size_t off = (size_t)c * GRIDN * GRIDN + idx;
        float v = lat[off];
        if (w >= 0) v = fmaxf(v + DT * d[c], 0.f);
        out_lat[off] = v * DECAYF;
    }
}

extern "C" void kernel_launch(void* const* d_in, const int* in_sizes, int n_in,
                              void* d_out, int out_size, void* d_ws, size_t ws_size,
                              hipStream_t stream) {
    const float* pos = (const float*)d_in[0];
    const float* vel = (const float*)d_in[1];
    const float* lat = (const float*)d_in[2];
    const float* W1  = (const float*)d_in[3];
    const float* b1  = (const float*)d_in[4];
    const float* W2  = (const float*)d_in[5];
    const float* b2  = (const float*)d_in[6];

    float* out      = (float*)d_out;
    float* out_pos  = out;                 // (2, N)
    float* out_vel  = out + 2 * NAGENTS;   // (2, N)
    float* out_lat  = out + 4 * NAGENTS;   // (C, G, G)

    char* ws = (char*)d_ws;
    int*       winner = (int*)ws;                            // 4 MB
    float*     dp     = (float*)(ws + (4 << 20));            // 8 MB
    _Float16*  BT     = (_Float16*)(ws + (12 << 20));        // 16 MB
    unsigned*  W1p    = (unsigned*)(ws + (28 << 20));        // 3 KB
    unsigned*  W2p    = (unsigned*)(ws + (28 << 20) + 4096); // 2 KB

    const int ncell = GRIDN * GRIDN;

    k_boxT<<<ncell / 256, 256, 0, stream>>>(lat, BT, winner, W1, W2, W1p, W2p);
    k_agent<<<NAGENTS / 128, 256, 0, stream>>>(pos, vel, BT, W1p, b1, W2p, b2,
                                               out_pos, out_vel, dp, winner);
    k_update<<<ncell / 256, 256, 0, stream>>>(lat, winner, dp, out_lat);
}

// Round 12
// 62.754 us; speedup vs baseline: 5.3817x; 1.0041x over previous
//
#include <hip/hip_runtime.h>
#include <math.h>

#define GRIDN 1024
#define NAGENTS 262144
#define CCH 8
#define HIDDEN 64
#define DT 0.1f
#define DECAYF 0.99f
#define SENSOR_LEN 3.0f
// cos(0.6), sin(0.6)
#define COS_SA 0.82533561490967829724f
#define SIN_SA 0.56464247339503535720f

typedef __attribute__((ext_vector_type(8))) short short8;
typedef __attribute__((ext_vector_type(8))) _Float16 half8;
typedef __attribute__((ext_vector_type(4))) float f32x4;
typedef __attribute__((ext_vector_type(2))) _Float16 half2v;

// packed 2-way f16 dot with f32 accumulate: v_dot2_f32_f16
__device__ __forceinline__ float dot2f(unsigned a, unsigned b, float c) {
#if __has_builtin(__builtin_amdgcn_fdot2)
    return __builtin_amdgcn_fdot2(__builtin_bit_cast(half2v, a),
                                  __builtin_bit_cast(half2v, b), c, false);
#else
    half2v ha = __builtin_bit_cast(half2v, a), hb = __builtin_bit_cast(half2v, b);
    return c + (float)ha.x * (float)hb.x + (float)ha.y * (float)hb.y;
#endif
}

__device__ __forceinline__ unsigned packh(float a, float b) {
    _Float16 ha = (_Float16)a, hb = (_Float16)b;
    unsigned short ua = __builtin_bit_cast(unsigned short, ha);
    unsigned short ub = __builtin_bit_cast(unsigned short, hb);
    return (unsigned)ua | ((unsigned)ub << 16);
}

// tanh(x) = 1 - 2/(e^{2x}+1); inf-safe without clamping (exp2->inf => 1, ->0 => -1)
__device__ __forceinline__ float fast_tanh(float x) {
    float t = __builtin_amdgcn_exp2f(x * 2.88539008177792681472f);  // 2*log2(e)
    return fmaf(-2.0f, __builtin_amdgcn_rcpf(t + 1.0f), 1.0f);
}

// BT[x][y][c] = 3x3 torus box sum of channel c at (x,y), stored f16.
// Fused: winner init; block 0 packs W1^T MFMA A-fragments and W2 dot2 pairs.
// W1T[mt*64+l] = uint4 of 8 f16: A[row=(l&15)+16mt][k=8*(l>>4)+j] = W1[k][row],
//   zero for k>=24 (K padded 24->32; also kills g==3 lanes' B garbage).
// W2p[pg*16+k] = (f16(W2[2pg][k]), f16(W2[2pg+1][k])), pg=0..31, k<10 (pad 16)
__global__ void __launch_bounds__(256) k_boxT(const float* __restrict__ lat,
                                              _Float16* __restrict__ BT,
                                              int* __restrict__ winner,
                                              const float* __restrict__ W1,
                                              const float* __restrict__ W2,
                                              uint4* __restrict__ W1T,
                                              unsigned* __restrict__ W2p) {
    if (blockIdx.x == 0) {
        int t = threadIdx.x;
        {
            int mt = t >> 6, l = t & 63;
            int g = l >> 4, col = (l & 15) + 16 * mt;
            unsigned u[4];
#pragma unroll
            for (int jj = 0; jj < 4; ++jj) {
                int k0 = 8 * g + 2 * jj, k1 = k0 + 1;
                float v0 = (k0 < 24) ? W1[k0 * HIDDEN + col] : 0.f;
                float v1 = (k1 < 24) ? W1[k1 * HIDDEN + col] : 0.f;
                u[jj] = packh(v0, v1);
            }
            W1T[t] = make_uint4(u[0], u[1], u[2], u[3]);
        }
        for (int q = t; q < 512; q += 256) {
            int pg = q >> 4, k = q & 15;
            unsigned v = 0;
            if (k < 10) v = packh(W2[(2 * pg) * 10 + k], W2[(2 * pg + 1) * 10 + k]);
            W2p[q] = v;
        }
    }
    int idx = blockIdx.x * blockDim.x + threadIdx.x;  // 0 .. 1M-1
    winner[idx] = -1;
    int x = idx >> 10, y = idx & (GRIDN - 1);
    int xm = (x + GRIDN - 1) & (GRIDN - 1), xp = (x + 1) & (GRIDN - 1);
    int ym = (y + GRIDN - 1) & (GRIDN - 1), yp = (y + 1) & (GRIDN - 1);
    _Float16 out[CCH];
#pragma unroll
    for (int c = 0; c < CCH; ++c) {
        const float* L = lat + (size_t)c * GRIDN * GRIDN;
        const float* r0 = L + xm * GRIDN;
        const float* r1 = L + x * GRIDN;
        const float* r2 = L + xp * GRIDN;
        float s = r0[ym] + r0[y] + r0[yp]
                + r1[ym] + r1[y] + r1[yp]
                + r2[ym] + r2[y] + r2[yp];
        out[c] = (_Float16)s;
    }
    *(short8*)(BT + (size_t)idx * CCH) = *(const short8*)out;
}

// MFMA agent kernel. Block = 4 waves = 256 agents; each wave independently
// handles 64 agents in 4 rounds of 16.
// Layer 1 as D1^T = W1^T (A, prepacked frags) x x^T (B = the sensor gather
// itself: lane l = sensor (l>>4) of agent (l&15) -- zero relayout).
// C-frag (col=agent l&15, row=hidden (l>>4)*4+r+16mt, m89 layout) -> tanh in
// register -> f16 pairs -> LDS transpose hB[agent][hidden-pair] (pitch 36:
// b64-aligned writes, b128-aligned reads) -> layer 2 dot2 with lane = agent.
__global__ void __launch_bounds__(256) k_agent(
    const float* __restrict__ pos, const float* __restrict__ vel,
    const _Float16* __restrict__ BT,
    const uint4* __restrict__ W1T, const float* __restrict__ b1,
    const unsigned* __restrict__ W2p, const float* __restrict__ b2,
    float* __restrict__ out_pos, float* __restrict__ out_vel,
    float* __restrict__ dp, int* __restrict__ winner) {
    __shared__ unsigned hB[4][64][36];  // [wave][agent][hidden-pair u32], pitch 36

    int lane = threadIdx.x & 63;
    int wq = __builtin_amdgcn_readfirstlane(threadIdx.x >> 6);
    int wavebase = blockIdx.x * 256 + wq * 64;
    int sub = lane & 15, g = lane >> 4;

    // preload A-fragments (W1^T) and bias fragments
    half8 afrag[4];
    f32x4 b1fr[4];
#pragma unroll
    for (int mt = 0; mt < 4; ++mt) {
        afrag[mt] = __builtin_bit_cast(half8, W1T[mt * 64 + lane]);
        b1fr[mt] = *(const f32x4*)(b1 + g * 4 + 16 * mt);  // rows g*4+r+16mt
    }

    // ---- phase 1: sense (gather IS the B-fragment); g==3 lanes do winner ----
    half8 bfrag[4];
#pragma unroll
    for (int t = 0; t < 4; ++t) {
        int a = wavebase + 16 * t + sub;
        float px = pos[a], py = pos[a + NAGENTS];
        if (g < 3) {
            float vx = vel[a], vy = vel[a + NAGENTS];
            float r2 = vx * vx + vy * vy;
            float ct, st;
            if (r2 > 0.f) {
                float inv = rsqrtf(r2);
                ct = vx * inv;
                st = vy * inv;
            } else {
                ct = 1.f;  // atan2(0,0) = 0
                st = 0.f;
            }
            float dx, dy;  // sensor g: 0 front, 1 left(+0.6), 2 right(-0.6)
            if (g == 0)      { dx = ct;                        dy = st; }
            else if (g == 1) { dx = ct * COS_SA - st * SIN_SA; dy = st * COS_SA + ct * SIN_SA; }
            else             { dx = ct * COS_SA + st * SIN_SA; dy = st * COS_SA - ct * SIN_SA; }
            int gx = ((int)rintf(px + SENSOR_LEN * dx) + GRIDN) & (GRIDN - 1);
            int gy = ((int)rintf(py + SENSOR_LEN * dy) + GRIDN) & (GRIDN - 1);
            bfrag[t] = *(const half8*)(BT + ((size_t)(gx << 10) + gy) * CCH);
        } else {
            uint4 z = make_uint4(0, 0, 0, 0);  // avoid 0*NaN in the K-pad region
            bfrag[t] = __builtin_bit_cast(half8, z);
            int wx = (int)rintf(px) & (GRIDN - 1);
            int wy = (int)rintf(py) & (GRIDN - 1);
            atomicMax(&winner[(wx << 10) + wy], a);
        }
    }

    // ---- phase 2: MFMA layer 1 + tanh + LDS transpose ----
#pragma unroll
    for (int t = 0; t < 4; ++t) {
        int al = 16 * t + sub;  // local agent index this lane's C-col maps to
#pragma unroll
        for (int mt = 0; mt < 4; ++mt) {
            f32x4 acc = __builtin_amdgcn_mfma_f32_16x16x32_f16(
                afrag[mt], bfrag[t], b1fr[mt], 0, 0, 0);
            // acc[r] = h[agent al][hidden g*4+r+16mt]
            unsigned p01 = packh(fast_tanh(acc[0]), fast_tanh(acc[1]));
            unsigned p23 = packh(fast_tanh(acc[2]), fast_tanh(acc[3]));
            hB[wq][al][2 * g + 8 * mt + 0] = p01;
            hB[wq][al][2 * g + 8 * mt + 1] = p23;
        }
    }
    __syncthreads();

    // ---- phase 3: layer 2 (lane = agent), dot2 vs prepacked W2 pairs ----
    int i = wavebase + lane;
    float o[2 + CCH];
#pragma unroll
    for (int k = 0; k < 2 + CCH; ++k) o[k] = b2[k];
#pragma unroll
    for (int blk = 0; blk < 8; ++blk) {
        uint4 hh = *(const uint4*)&hB[wq][lane][blk * 4];  // pairs pg=4blk..4blk+3
        unsigned hp[4] = {hh.x, hh.y, hh.z, hh.w};
#pragma unroll
        for (int q = 0; q < 4; ++q) {
            const unsigned* wr = W2p + (blk * 4 + q) * 16;  // wave-uniform
#pragma unroll
            for (int k = 0; k < 2 + CCH; ++k) o[k] = dot2f(hp[q], wr[k], o[k]);
        }
    }

    // ---- epilogue: all outputs from this lane ----
    float px = pos[i], py = pos[i + NAGENTS];
    float nvx = o[0], nvy = o[1];
    float npx = px + nvx * DT;
    if (npx >= (float)GRIDN) npx -= (float)GRIDN;
    if (npx < 0.f) npx += (float)GRIDN;
    float npy = py + nvy * DT;
    if (npy >= (float)GRIDN) npy -= (float)GRIDN;
    if (npy < 0.f) npy += (float)GRIDN;

    out_pos[i] = npx;
    out_pos[i + NAGENTS] = npy;
    out_vel[i] = nvx;
    out_vel[i + NAGENTS] = nvy;

    float4* dpp = (float4*)(dp + (size_t)i * CCH);
    dpp[0] = make_float4(o[2], o[3], o[4], o[5]);
    dpp[1] = make_float4(o[6], o[7], o[8], o[9]);
}

__global__ void __launch_bounds__(256) k_update(const float* __restrict__ lat,
                                                const int* __restrict__ winner,
                                                const float* __restrict__ dp,
                                                float* __restrict__ out_lat) {
    int idx = blockIdx.x * blockDim.x + threadIdx.x;  // cell index
    int w = winner[idx];
    float d[CCH];
    if (w >= 0) {
        const float4* dpp = (const float4*)(dp + (size_t)w * CCH);
        float4 a = dpp[0], b = dpp[1];
        d[0] = a.x; d[1] = a.y; d[2] = a.z; d[3] = a.w;
        d[4] = b.x; d[5] = b.y; d[6] = b.z; d[7] = b.w;
    }
#pragma unroll
    for (int c = 0; c < CCH; ++c) {
        size_t off = (size_t)c * GRIDN * GRIDN + idx;
        float v = lat[off];
        if (w >= 0) v = fmaxf(v + DT * d[c], 0.f);
        out_lat[off] = v * DECAYF;
    }
}

extern "C" void kernel_launch(void* const* d_in, const int* in_sizes, int n_in,
                              void* d_out, int out_size, void* d_ws, size_t ws_size,
                              hipStream_t stream) {
    const float* pos = (const float*)d_in[0];
    const float* vel = (const float*)d_in[1];
    const float* lat = (const float*)d_in[2];
    const float* W1  = (const float*)d_in[3];
    const float* b1  = (const float*)d_in[4];
    const float* W2  = (const float*)d_in[5];
    const float* b2  = (const float*)d_in[6];

    float* out      = (float*)d_out;
    float* out_pos  = out;                 // (2, N)
    float* out_vel  = out + 2 * NAGENTS;   // (2, N)
    float* out_lat  = out + 4 * NAGENTS;   // (C, G, G)

    char* ws = (char*)d_ws;
    int*       winner = (int*)ws;                            // 4 MB
    float*     dp     = (float*)(ws + (4 << 20));            // 8 MB
    _Float16*  BT     = (_Float16*)(ws + (12 << 20));        // 16 MB
    uint4*     W1T    = (uint4*)(ws + (28 << 20));           // 4 KB
    unsigned*  W2p    = (unsigned*)(ws + (28 << 20) + 8192); // 2 KB

    const int ncell = GRIDN * GRIDN;

    k_boxT<<<ncell / 256, 256, 0, stream>>>(lat, BT, winner, W1, W2, W1T, W2p);
    k_agent<<<NAGENTS / 256, 256, 0, stream>>>(pos, vel, BT, W1T, b1, W2p, b2,
                                               out_pos, out_vel, dp, winner);
    k_update<<<ncell / 256, 256, 0, stream>>>(lat, winner, dp, out_lat);
}